// Round 1
// baseline (2106.016 us; speedup 1.0000x reference)
//
#include <hip/hip_runtime.h>
#include <hip/hip_bf16.h>

#define S 4096
#define L 16
#define WD 128
#define CD 32
#define NF 5
#define KW 5
#define H 32
#define IN_DIM (WD + NF)   // 133
#define NTAGS 45

__device__ inline float fexp2(float x) {
#if __has_builtin(__builtin_amdgcn_exp2f)
    return __builtin_amdgcn_exp2f(x);
#else
    return exp2f(x);
#endif
}
__device__ inline float frcp(float x) {
#if __has_builtin(__builtin_amdgcn_rcpf)
    return __builtin_amdgcn_rcpf(x);
#else
    return 1.0f / x;
#endif
}
// sigmoid(x) = 1 / (1 + 2^(-x*log2e))
__device__ inline float fsigmoid(float x) {
    return frcp(1.0f + fexp2(-1.442695040888963f * x));
}

// ---------------------------------------------------------------------------
// Kernel A: per-word feature build + input projection for both LSTM directions
// grid = S blocks, 256 threads
// ---------------------------------------------------------------------------
__global__ __launch_bounds__(256)
void prep_kernel(const int* __restrict__ word_ids,
                 const int* __restrict__ char_ids,
                 const float* __restrict__ word_emb,
                 const float* __restrict__ char_emb,
                 const float* __restrict__ conv_w,
                 const float* __restrict__ conv_b,
                 const float* __restrict__ w_ih_f,
                 const float* __restrict__ b_ih_f,
                 const float* __restrict__ b_hh_f,
                 const float* __restrict__ w_ih_b,
                 const float* __restrict__ b_ih_b,
                 const float* __restrict__ b_hh_b,
                 float* __restrict__ pre_f,
                 float* __restrict__ pre_b)
{
    __shared__ float rep[IN_DIM];
    __shared__ float ce[L][CD];
    __shared__ float convout[NF][L];

    const int s   = blockIdx.x;
    const int tid = threadIdx.x;

    // word embedding -> rep[0..127]
    if (tid < WD) {
        rep[tid] = word_emb[(size_t)word_ids[s] * WD + tid];
    }
    // char embeddings -> ce[l][c]  (512 floats, 2 per thread)
    for (int i = tid; i < L * CD; i += 256) {
        int l = i / CD, c = i % CD;
        ce[l][c] = char_emb[(size_t)char_ids[s * L + l] * CD + c];
    }
    __syncthreads();

    // conv1d (pad=2, cross-correlation) -> convout[f][l]
    if (tid < NF * L) {
        int f = tid / L, l = tid % L;
        float acc = conv_b[f];
#pragma unroll
        for (int k = 0; k < KW; ++k) {
            int ll = l + k - 2;
            if (ll >= 0 && ll < L) {
#pragma unroll
                for (int c = 0; c < CD; ++c)
                    acc += ce[ll][c] * conv_w[f * CD * KW + c * KW + k];
            }
        }
        convout[f][l] = acc;
    }
    __syncthreads();

    // max-pool over L -> rep[128..132]
    if (tid < NF) {
        float m = convout[tid][0];
#pragma unroll
        for (int l = 1; l < L; ++l) m = fmaxf(m, convout[tid][l]);
        rep[WD + tid] = m;
    }
    __syncthreads();

    // input projection: pre[s][g] = b_ih[g]+b_hh[g] + rep . w_ih[g,:]
    {
        int g = tid & 127;
        bool fw = (tid < 128);
        const float* wih = fw ? w_ih_f : w_ih_b;
        float acc = fw ? (b_ih_f[g] + b_hh_f[g]) : (b_ih_b[g] + b_hh_b[g]);
        const float* wrow = wih + (size_t)g * IN_DIM;
        for (int j = 0; j < IN_DIM; ++j)
            acc += rep[j] * wrow[j];
        (fw ? pre_f : pre_b)[(size_t)s * 128 + g] = acc;
    }
}

// ---------------------------------------------------------------------------
// Kernel B: the sequential LSTM scan. grid = 2 blocks (fwd, bwd), 64 threads.
// Lane l owns gate rows l and l+64. h lives in lanes 0..31, broadcast via
// v_readlane. Wave-synchronous: no barriers.
// ---------------------------------------------------------------------------
__global__ __launch_bounds__(64, 1)
void lstm_scan(const float* __restrict__ pre_f,
               const float* __restrict__ pre_b,
               const float* __restrict__ w_hh_f,
               const float* __restrict__ w_hh_b,
               float* __restrict__ hf,
               float* __restrict__ hb)
{
    const bool fwd = (blockIdx.x == 0);
    const float* __restrict__ pre = fwd ? pre_f : pre_b;
    const float* __restrict__ whh = fwd ? w_hh_f : w_hh_b;
    float* __restrict__ hout      = fwd ? hf : hb;
    const int dir  = fwd ? 1 : -1;
    const int idx0 = fwd ? 0 : (S - 1);

    const int l  = threadIdx.x;      // 0..63
    const int g0 = l;                // gate row l      (i for l<32, f for l>=32)
    const int g1 = l + 64;           // gate row l+64   (g for l<32, o for l>=32)

    // hold w_hh rows in registers
    float w0[H], w1[H];
#pragma unroll
    for (int j = 0; j < H; ++j) {
        w0[j] = whh[g0 * H + j];
        w1[j] = whh[g1 * H + j];
    }

    const bool isG = (l < 32);                   // second gate is tanh for l<32
    const float bMul = isG ? 2.0f : 1.0f;        // tanh(x) = 2*sig(2x)-1
    const float bScl = isG ? 2.0f : 1.0f;
    const float bOff = isG ? -1.0f : 0.0f;

    float h = 0.0f, c = 0.0f;
    int idx = idx0;
    float p0 = pre[(size_t)idx * 128 + g0];
    float p1 = pre[(size_t)idx * 128 + g1];

    for (int t = 0; t < S; ++t) {
        // prefetch next step's pre values (clamped; last iter loads redundantly)
        int nidx = idx + dir;
        int cl = nidx < 0 ? 0 : (nidx >= S ? S - 1 : nidx);
        float np0 = pre[(size_t)cl * 128 + g0];
        float np1 = pre[(size_t)cl * 128 + g1];

        // gate pre-activations: acc = pre + h . w_hh[row,:]
        float acc0 = p0, acc1 = p1;
#pragma unroll
        for (int j = 0; j < H; ++j) {
            float hj = __int_as_float(
                __builtin_amdgcn_readlane(__float_as_int(h), j));
            acc0 = fmaf(hj, w0[j], acc0);
            acc1 = fmaf(hj, w1[j], acc1);
        }

        // activations
        float A = fsigmoid(acc0);                       // i (l<32) / f (l>=32)
        float B = fmaf(bScl, fsigmoid(bMul * acc1), bOff); // g (tanh) / o (sig)

        // swap halves: lanes 0..31 receive f and o
        float Asw = __shfl_xor(A, 32, 64);   // f
        float Bsw = __shfl_xor(B, 32, 64);   // o

        // cell update (valid in lanes 0..31; lanes 32..63 compute junk)
        c = fmaf(Asw, c, A * B);                       // c = f*c + i*g
        float th = fmaf(2.0f, fsigmoid(2.0f * c), -1.0f); // tanh(c)
        h = Bsw * th;                                  // h = o * tanh(c)

        if (l < 32) hout[(size_t)idx * H + l] = h;

        idx = nidx; p0 = np0; p1 = np1;
    }
}

// ---------------------------------------------------------------------------
// Kernel C: output projection  out = [hf|hb] @ out_w.T + out_b
// grid = S blocks, 64 threads
// ---------------------------------------------------------------------------
__global__ __launch_bounds__(64)
void out_kernel(const float* __restrict__ hf,
                const float* __restrict__ hb,
                const float* __restrict__ out_w,
                const float* __restrict__ out_b,
                float* __restrict__ out)
{
    __shared__ float hh[2 * H];
    const int s = blockIdx.x, tid = threadIdx.x;
    if (tid < H)       hh[tid] = hf[(size_t)s * H + tid];
    else               hh[tid] = hb[(size_t)s * H + (tid - H)];
    __syncthreads();
    if (tid < NTAGS) {
        float acc = out_b[tid];
#pragma unroll
        for (int j = 0; j < 2 * H; ++j)
            acc = fmaf(hh[j], out_w[tid * 2 * H + j], acc);
        out[(size_t)s * NTAGS + tid] = acc;
    }
}

extern "C" void kernel_launch(void* const* d_in, const int* in_sizes, int n_in,
                              void* d_out, int out_size, void* d_ws, size_t ws_size,
                              hipStream_t stream) {
    const int*   word_ids = (const int*)  d_in[0];
    const int*   char_ids = (const int*)  d_in[1];
    const float* word_emb = (const float*)d_in[2];
    const float* char_emb = (const float*)d_in[3];
    const float* conv_w   = (const float*)d_in[4];
    const float* conv_b   = (const float*)d_in[5];
    const float* w_ih_f   = (const float*)d_in[6];
    const float* w_hh_f   = (const float*)d_in[7];
    const float* b_ih_f   = (const float*)d_in[8];
    const float* b_hh_f   = (const float*)d_in[9];
    const float* w_ih_b   = (const float*)d_in[10];
    const float* w_hh_b   = (const float*)d_in[11];
    const float* b_ih_b   = (const float*)d_in[12];
    const float* b_hh_b   = (const float*)d_in[13];
    const float* out_w    = (const float*)d_in[14];
    const float* out_b    = (const float*)d_in[15];
    float* out = (float*)d_out;

    float* ws    = (float*)d_ws;
    float* pre_f = ws;                       // S*128
    float* pre_b = pre_f + (size_t)S * 128;  // S*128
    float* hf    = pre_b + (size_t)S * 128;  // S*H
    float* hb    = hf    + (size_t)S * H;    // S*H

    prep_kernel<<<S, 256, 0, stream>>>(word_ids, char_ids, word_emb, char_emb,
                                       conv_w, conv_b,
                                       w_ih_f, b_ih_f, b_hh_f,
                                       w_ih_b, b_ih_b, b_hh_b,
                                       pre_f, pre_b);
    lstm_scan<<<2, 64, 0, stream>>>(pre_f, pre_b, w_hh_f, w_hh_b, hf, hb);
    out_kernel<<<S, 64, 0, stream>>>(hf, hb, out_w, out_b, out);
}

// Round 2
// 1531.504 us; speedup vs baseline: 1.3751x; 1.3751x over previous
//
#include <hip/hip_runtime.h>
#include <hip/hip_bf16.h>

#define S 4096
#define L 16
#define WD 128
#define CD 32
#define NF 5
#define KW 5
#define H 32
#define IN_DIM (WD + 5)    // 133
#define WPAD 136           // padded row stride (16B-aligned rows)
#define NTAGS 45

typedef float v2f __attribute__((ext_vector_type(2)));
typedef float v4f __attribute__((ext_vector_type(4)));

__device__ inline float fexp2(float x) { return __builtin_amdgcn_exp2f(x); }
__device__ inline float frcp(float x)  { return __builtin_amdgcn_rcpf(x); }
// sigmoid(x) = 1 / (1 + 2^(-x*log2e))
__device__ inline float fsigmoid(float x) {
    return frcp(1.0f + fexp2(-1.442695040888963f * x));
}
__device__ inline float rl(float v, int lane) {
    return __int_as_float(__builtin_amdgcn_readlane(__float_as_int(v), lane));
}

// ---------------------------------------------------------------------------
// Kernel 0: pad w_ih_f / w_ih_b rows (133 -> 136) so prep can use float4 loads
// grid = 256 blocks (one per gate row, fwd then bwd), 64 threads
// ---------------------------------------------------------------------------
__global__ __launch_bounds__(64)
void pad_w_kernel(const float* __restrict__ wf, const float* __restrict__ wb,
                  float* __restrict__ wpad)
{
    const int r = blockIdx.x;
    const float* src = (r < 128) ? (wf + (size_t)r * IN_DIM)
                                 : (wb + (size_t)(r - 128) * IN_DIM);
    for (int j = threadIdx.x; j < WPAD; j += 64)
        wpad[(size_t)r * WPAD + j] = (j < IN_DIM) ? src[j] : 0.0f;
}

// ---------------------------------------------------------------------------
// Kernel A: per-word feature build + input projection for both directions
// grid = S blocks, 256 threads
// ---------------------------------------------------------------------------
__global__ __launch_bounds__(256)
void prep_kernel(const int* __restrict__ word_ids,
                 const int* __restrict__ char_ids,
                 const float* __restrict__ word_emb,
                 const float* __restrict__ char_emb,
                 const float* __restrict__ conv_w,
                 const float* __restrict__ conv_b,
                 const float* __restrict__ wpad,     // [256][WPAD]
                 const float* __restrict__ b_ih_f,
                 const float* __restrict__ b_hh_f,
                 const float* __restrict__ b_ih_b,
                 const float* __restrict__ b_hh_b,
                 float* __restrict__ pre_f,
                 float* __restrict__ pre_b)
{
    __shared__ __align__(16) float rep[WPAD];
    __shared__ float ce[L][CD];
    __shared__ float convout[NF][L];

    const int s   = blockIdx.x;
    const int tid = threadIdx.x;

    if (tid < WD) rep[tid] = word_emb[(size_t)word_ids[s] * WD + tid];
    if (tid >= WD && tid < WPAD) rep[tid] = 0.0f;   // zero pad tail (incl. 133..135)

    for (int i = tid; i < L * CD; i += 256) {
        int l = i / CD, c = i % CD;
        ce[l][c] = char_emb[(size_t)char_ids[s * L + l] * CD + c];
    }
    __syncthreads();

    if (tid < NF * L) {
        int f = tid / L, l = tid % L;
        float acc = conv_b[f];
#pragma unroll
        for (int k = 0; k < KW; ++k) {
            int ll = l + k - 2;
            if (ll >= 0 && ll < L) {
#pragma unroll
                for (int c = 0; c < CD; ++c)
                    acc += ce[ll][c] * conv_w[f * CD * KW + c * KW + k];
            }
        }
        convout[f][l] = acc;
    }
    __syncthreads();

    if (tid < NF) {
        float m = convout[tid][0];
#pragma unroll
        for (int l = 1; l < L; ++l) m = fmaxf(m, convout[tid][l]);
        rep[WD + tid] = m;
    }
    __syncthreads();

    // projection: 34 float4 fmas per gate row
    {
        const int g = tid & 127;
        const bool fw = (tid < 128);
        const float* wrow = wpad + ((size_t)(fw ? g : g + 128)) * WPAD;
        float acc = fw ? (b_ih_f[g] + b_hh_f[g]) : (b_ih_b[g] + b_hh_b[g]);
        v4f av = {0.f, 0.f, 0.f, 0.f};
#pragma unroll
        for (int jj = 0; jj < WPAD / 4; ++jj) {
            v4f wv = *(const v4f*)(wrow + 4 * jj);
            v4f rv = *(const v4f*)(&rep[4 * jj]);
            av = __builtin_elementwise_fma(wv, rv, av);
        }
        acc += (av.x + av.y) + (av.z + av.w);
        (fw ? pre_f : pre_b)[(size_t)s * 128 + g] = acc;
    }
}

// ---------------------------------------------------------------------------
// Kernel B: sequential LSTM scan. grid = 2 blocks (fwd, bwd), 64 threads.
// Lane l owns gate rows l and l+64. Packed-f32 dot product, prefetch depth 4.
// ---------------------------------------------------------------------------
#define PF 4
__global__ __launch_bounds__(64, 1)
void lstm_scan(const float* __restrict__ pre_f,
               const float* __restrict__ pre_b,
               const float* __restrict__ w_hh_f,
               const float* __restrict__ w_hh_b,
               float* __restrict__ hf,
               float* __restrict__ hb)
{
    const bool fwd = (blockIdx.x == 0);
    const float* __restrict__ pre = fwd ? pre_f : pre_b;
    const float* __restrict__ whh = fwd ? w_hh_f : w_hh_b;
    float* __restrict__ hout      = fwd ? hf : hb;
    const int dir  = fwd ? 1 : -1;
    const int idx0 = fwd ? 0 : (S - 1);
    const int step = dir * 128;

    const int l  = threadIdx.x;      // 0..63
    const int g0 = l;                // rows: i (l<32) / f (l>=32)
    const int g1 = l + 64;           // rows: g (l<32) / o (l>=32)

    // w_hh rows as float2 (rows are 32 floats -> 128B aligned)
    v2f w0[H / 2], w1[H / 2];
    {
        const v2f* wr0 = (const v2f*)(whh + (size_t)g0 * H);
        const v2f* wr1 = (const v2f*)(whh + (size_t)g1 * H);
#pragma unroll
        for (int j = 0; j < H / 2; ++j) { w0[j] = wr0[j]; w1[j] = wr1[j]; }
    }

    const bool isG = (l < 32);
    const float bMul = isG ? 2.0f : 1.0f;
    const float bScl = isG ? 2.0f : 1.0f;
    const float bOff = isG ? -1.0f : 0.0f;

    float h = 0.0f, c = 0.0f;
    int idx = idx0;
    const float* ptr = pre + (size_t)idx0 * 128;

    // prefetch pipeline, depth PF
    float pp0[PF], pp1[PF];
#pragma unroll
    for (int u = 0; u < PF; ++u) {
        pp0[u] = ptr[(long)step * u + g0];
        pp1[u] = ptr[(long)step * u + g1];
    }

    for (int t = 0; t < S; t += PF) {
#pragma unroll
        for (int u = 0; u < PF; ++u) {
            const float cp0 = pp0[u], cp1 = pp1[u];
            // refill slot u with step t+u+PF (overreach stays inside ws layout)
            pp0[u] = ptr[(long)step * PF + g0];
            pp1[u] = ptr[(long)step * PF + g1];

            // gate pre-activations via packed fma; h broadcast as sgpr pairs
            v2f a0; a0.x = cp0; a0.y = 0.0f;
            v2f a1; a1.x = cp1; a1.y = 0.0f;
#pragma unroll
            for (int jp = 0; jp < H / 2; ++jp) {
                v2f hp;
                hp.x = rl(h, 2 * jp);
                hp.y = rl(h, 2 * jp + 1);
                a0 = __builtin_elementwise_fma(hp, w0[jp], a0);
                a1 = __builtin_elementwise_fma(hp, w1[jp], a1);
            }
            const float acc0 = a0.x + a0.y;
            const float acc1 = a1.x + a1.y;

            const float A = fsigmoid(acc0);                          // i / f
            const float B = fmaf(bScl, fsigmoid(bMul * acc1), bOff); // tanh(g) / o

            const float Asw = __shfl_xor(A, 32, 64);  // f to lanes 0..31
            const float Bsw = __shfl_xor(B, 32, 64);  // o to lanes 0..31

            c = fmaf(Asw, c, A * B);                          // c = f*c + i*g
            const float th = fmaf(2.0f, fsigmoid(2.0f * c), -1.0f);
            h = Bsw * th;                                     // h = o*tanh(c)

            if (l < 32) hout[(size_t)idx * H + l] = h;

            idx += dir; ptr += step;
        }
    }
}

// ---------------------------------------------------------------------------
// Kernel C: output projection  out = [hf|hb] @ out_w.T + out_b
// grid = S blocks, 64 threads. out_w rows are 64 floats (16B-aligned).
// ---------------------------------------------------------------------------
__global__ __launch_bounds__(64)
void out_kernel(const float* __restrict__ hf,
                const float* __restrict__ hb,
                const float* __restrict__ out_w,
                const float* __restrict__ out_b,
                float* __restrict__ out)
{
    __shared__ __align__(16) float hh[2 * H];
    const int s = blockIdx.x, tid = threadIdx.x;
    if (tid < H) hh[tid] = hf[(size_t)s * H + tid];
    else         hh[tid] = hb[(size_t)s * H + (tid - H)];
    __syncthreads();
    if (tid < NTAGS) {
        v4f av = {0.f, 0.f, 0.f, 0.f};
        const float* wrow = out_w + (size_t)tid * 2 * H;
#pragma unroll
        for (int jj = 0; jj < (2 * H) / 4; ++jj) {
            v4f wv = *(const v4f*)(wrow + 4 * jj);
            v4f hv = *(const v4f*)(&hh[4 * jj]);
            av = __builtin_elementwise_fma(wv, hv, av);
        }
        out[(size_t)s * NTAGS + tid] =
            out_b[tid] + (av.x + av.y) + (av.z + av.w);
    }
}

extern "C" void kernel_launch(void* const* d_in, const int* in_sizes, int n_in,
                              void* d_out, int out_size, void* d_ws, size_t ws_size,
                              hipStream_t stream) {
    const int*   word_ids = (const int*)  d_in[0];
    const int*   char_ids = (const int*)  d_in[1];
    const float* word_emb = (const float*)d_in[2];
    const float* char_emb = (const float*)d_in[3];
    const float* conv_w   = (const float*)d_in[4];
    const float* conv_b   = (const float*)d_in[5];
    const float* w_ih_f   = (const float*)d_in[6];
    const float* w_hh_f   = (const float*)d_in[7];
    const float* b_ih_f   = (const float*)d_in[8];
    const float* b_hh_f   = (const float*)d_in[9];
    const float* w_ih_b   = (const float*)d_in[10];
    const float* w_hh_b   = (const float*)d_in[11];
    const float* b_ih_b   = (const float*)d_in[12];
    const float* b_hh_b   = (const float*)d_in[13];
    const float* out_w    = (const float*)d_in[14];
    const float* out_b    = (const float*)d_in[15];
    float* out = (float*)d_out;

    float* ws    = (float*)d_ws;
    float* pre_f = ws;                         // S*128
    float* pre_b = pre_f + (size_t)S * 128;    // S*128
    float* hf    = pre_b + (size_t)S * 128;    // S*H
    float* hb    = hf    + (size_t)S * H;      // S*H
    float* wpad  = hb    + (size_t)S * H;      // 256*WPAD

    pad_w_kernel<<<256, 64, 0, stream>>>(w_ih_f, w_ih_b, wpad);
    prep_kernel<<<S, 256, 0, stream>>>(word_ids, char_ids, word_emb, char_emb,
                                       conv_w, conv_b, wpad,
                                       b_ih_f, b_hh_f, b_ih_b, b_hh_b,
                                       pre_f, pre_b);
    lstm_scan<<<2, 64, 0, stream>>>(pre_f, pre_b, w_hh_f, w_hh_b, hf, hb);
    out_kernel<<<S, 64, 0, stream>>>(hf, hb, out_w, out_b, out);
}

// Round 3
// 1245.349 us; speedup vs baseline: 1.6911x; 1.2298x over previous
//
#include <hip/hip_runtime.h>
#include <hip/hip_bf16.h>

#define S 4096
#define L 16
#define WD 128
#define CD 32
#define NF 5
#define KW 5
#define H 32
#define IN_DIM (WD + 5)    // 133
#define WPAD 136           // padded row stride (16B-aligned rows)
#define NTAGS 45

typedef float v2f __attribute__((ext_vector_type(2)));
typedef float v4f __attribute__((ext_vector_type(4)));

#define LOG2E 1.4426950408889634f

__device__ inline float fexp2(float x) { return __builtin_amdgcn_exp2f(x); }
__device__ inline float frcp(float x)  { return __builtin_amdgcn_rcpf(x); }
__device__ inline float rl(float v, int lane) {
    return __int_as_float(__builtin_amdgcn_readlane(__float_as_int(v), lane));
}

// exchange half-waves: returned value, in lanes 0..31, holds x's lanes 32..63.
// (upper-lane contents of the result are junk we never consume.)
__device__ inline float swap_half(float x) {
#if __has_builtin(__builtin_amdgcn_permlane32_swap)
    typedef unsigned uv2 __attribute__((ext_vector_type(2)));
    uv2 r = __builtin_amdgcn_permlane32_swap(__float_as_uint(x),
                                             __float_as_uint(x), false, false);
    return __uint_as_float(r.y);   // vsrc_new[0:31] = vdst_old[32:63]
#else
    return __shfl_xor(x, 32, 64);
#endif
}

// ---------------------------------------------------------------------------
// Kernel 0: pad w_ih rows (133 -> 136) so prep can use float4 loads
// ---------------------------------------------------------------------------
__global__ __launch_bounds__(64)
void pad_w_kernel(const float* __restrict__ wf, const float* __restrict__ wb,
                  float* __restrict__ wpad)
{
    const int r = blockIdx.x;
    const float* src = (r < 128) ? (wf + (size_t)r * IN_DIM)
                                 : (wb + (size_t)(r - 128) * IN_DIM);
    for (int j = threadIdx.x; j < WPAD; j += 64)
        wpad[(size_t)r * WPAD + j] = (j < IN_DIM) ? src[j] : 0.0f;
}

// ---------------------------------------------------------------------------
// Kernel A: feature build + input projection (both directions), pre-scaled by
// -log2e (and -2log2e for the tanh/g rows) so the scan's activations are
// exp2-ready with no on-chain multiply.
// ---------------------------------------------------------------------------
__global__ __launch_bounds__(256)
void prep_kernel(const int* __restrict__ word_ids,
                 const int* __restrict__ char_ids,
                 const float* __restrict__ word_emb,
                 const float* __restrict__ char_emb,
                 const float* __restrict__ conv_w,
                 const float* __restrict__ conv_b,
                 const float* __restrict__ wpad,     // [256][WPAD]
                 const float* __restrict__ b_ih_f,
                 const float* __restrict__ b_hh_f,
                 const float* __restrict__ b_ih_b,
                 const float* __restrict__ b_hh_b,
                 float* __restrict__ pre_f,
                 float* __restrict__ pre_b)
{
    __shared__ __align__(16) float rep[WPAD];
    __shared__ __align__(16) float ce[L][CD];
    __shared__ __align__(16) float cw[NF][KW][CD];   // transposed conv weights
    __shared__ float convout[NF][L];

    const int s   = blockIdx.x;
    const int tid = threadIdx.x;
    const int wid = word_ids[s];

    // word embedding -> rep[0..127] (float4)
    if (tid < WD / 4)
        *(v4f*)&rep[4 * tid] = *(const v4f*)&word_emb[(size_t)wid * WD + 4 * tid];
    if (tid >= WD && tid < WPAD) rep[tid] = 0.0f;

    // char embeddings (float4: rows are 32 floats, 128B)
    if (tid < L * CD / 4) {
        int l = tid / (CD / 4), c4 = tid % (CD / 4);
        *(v4f*)&ce[l][4 * c4] =
            *(const v4f*)&char_emb[(size_t)char_ids[s * L + l] * CD + 4 * c4];
    }
    // conv weights transposed: cw[f][k][c] = conv_w[f][c][k]
    for (int i = tid; i < NF * KW * CD; i += 256) {
        int f = i / (KW * CD), r = i % (KW * CD), k = r / CD, c = r % CD;
        cw[f][k][c] = conv_w[f * CD * KW + c * KW + k];
    }
    __syncthreads();

    if (tid < NF * L) {
        int f = tid / L, l = tid % L;
        v4f av = {0.f, 0.f, 0.f, 0.f};
#pragma unroll
        for (int k = 0; k < KW; ++k) {
            int ll = l + k - 2;
            if (ll >= 0 && ll < L) {
#pragma unroll
                for (int q = 0; q < CD / 4; ++q)
                    av = __builtin_elementwise_fma(*(const v4f*)&ce[ll][4 * q],
                                                   *(const v4f*)&cw[f][k][4 * q], av);
            }
        }
        convout[f][l] = conv_b[f] + (av.x + av.y) + (av.z + av.w);
    }
    __syncthreads();

    if (tid < NF) {
        float m = convout[tid][0];
#pragma unroll
        for (int l = 1; l < L; ++l) m = fmaxf(m, convout[tid][l]);
        rep[WD + tid] = m;
    }
    __syncthreads();

    {
        const int g = tid & 127;
        const bool fw = (tid < 128);
        const float* wrow = wpad + ((size_t)(fw ? g : g + 128)) * WPAD;
        float acc = fw ? (b_ih_f[g] + b_hh_f[g]) : (b_ih_b[g] + b_hh_b[g]);
        v4f av = {0.f, 0.f, 0.f, 0.f};
#pragma unroll
        for (int jj = 0; jj < WPAD / 4; ++jj) {
            v4f wv = *(const v4f*)(wrow + 4 * jj);
            v4f rv = *(const v4f*)(&rep[4 * jj]);
            av = __builtin_elementwise_fma(wv, rv, av);
        }
        acc += (av.x + av.y) + (av.z + av.w);
        // pre-scale: g rows (64..95) feed tanh -> -2*log2e; others sigmoid -> -log2e
        const float scl = (g >= 64 && g < 96) ? (-2.0f * LOG2E) : (-LOG2E);
        (fw ? pre_f : pre_b)[(size_t)s * 128 + g] = acc * scl;
    }
}

// ---------------------------------------------------------------------------
// Kernel B: sequential LSTM scan. 2 blocks (fwd/bwd) x 64 threads.
// Lane l owns gate rows l and l+64. Weights pre-scaled (anti-remat + shorter
// activation chain); permlane32_swap for the half exchange; split FMA chains.
// ---------------------------------------------------------------------------
#define PF 4
__global__ __launch_bounds__(64, 1)
void lstm_scan(const float* __restrict__ pre_f,
               const float* __restrict__ pre_b,
               const float* __restrict__ w_hh_f,
               const float* __restrict__ w_hh_b,
               float* __restrict__ hf,
               float* __restrict__ hb)
{
    const bool fwd = (blockIdx.x == 0);
    const float* __restrict__ pre = fwd ? pre_f : pre_b;
    const float* __restrict__ whh = fwd ? w_hh_f : w_hh_b;
    float* __restrict__ hout      = fwd ? hf : hb;
    const int dir  = fwd ? 1 : -1;
    const int idx0 = fwd ? 0 : (S - 1);
    const int step = dir * 128;

    const int l  = threadIdx.x;      // 0..63
    const int g0 = l;                // i (l<32) / f (l>=32) : sigmoid
    const int g1 = l + 64;           // g (l<32) / o (l>=32) : tanh / sigmoid

    const bool isG = (l < 32);
    const float s0 = -LOG2E;
    const float s1 = isG ? (-2.0f * LOG2E) : (-LOG2E);
    const float bScl = isG ? 2.0f : 1.0f;
    const float bOff = isG ? -1.0f : 0.0f;

    // w_hh rows, scaled into exp2 domain (computed values -> stay in VGPRs)
    v2f w0[H / 2], w1[H / 2];
    {
        const v2f* wr0 = (const v2f*)(whh + (size_t)g0 * H);
        const v2f* wr1 = (const v2f*)(whh + (size_t)g1 * H);
        v2f vs0; vs0.x = s0; vs0.y = s0;
        v2f vs1; vs1.x = s1; vs1.y = s1;
#pragma unroll
        for (int j = 0; j < H / 2; ++j) { w0[j] = wr0[j] * vs0; w1[j] = wr1[j] * vs1; }
    }

    float h = 0.0f, c = 0.0f;
    int idx = idx0;
    const float* ptr = pre + (size_t)idx0 * 128;

    float pp0[PF], pp1[PF];
#pragma unroll
    for (int u = 0; u < PF; ++u) {
        pp0[u] = ptr[(long)step * u + g0];
        pp1[u] = ptr[(long)step * u + g1];
    }

    for (int t = 0; t < S; t += PF) {
#pragma unroll
        for (int u = 0; u < PF; ++u) {
            const float cp0 = pp0[u], cp1 = pp1[u];
            pp0[u] = ptr[(long)step * PF + g0];   // refill PF steps ahead
            pp1[u] = ptr[(long)step * PF + g1];   // (overreach stays inside ws)

            // acc = scaled_pre + h . scaled_w  — 4 independent chains of 8
            v2f a0a; a0a.x = cp0; a0a.y = 0.0f;
            v2f a1a; a1a.x = cp1; a1a.y = 0.0f;
            v2f a0b = {0.f, 0.f}, a1b = {0.f, 0.f};
#pragma unroll
            for (int jp = 0; jp < 8; ++jp) {
                v2f hpa, hpb;
                hpa.x = rl(h, 2 * jp);      hpa.y = rl(h, 2 * jp + 1);
                hpb.x = rl(h, 2 * jp + 16); hpb.y = rl(h, 2 * jp + 17);
                a0a = __builtin_elementwise_fma(hpa, w0[jp], a0a);
                a0b = __builtin_elementwise_fma(hpb, w0[jp + 8], a0b);
                a1a = __builtin_elementwise_fma(hpa, w1[jp], a1a);
                a1b = __builtin_elementwise_fma(hpb, w1[jp + 8], a1b);
            }
            const v2f sv0 = a0a + a0b;           // v_pk_add_f32
            const v2f sv1 = a1a + a1b;
            const float acc0 = sv0.x + sv0.y;    // = -log2e * preact
            const float acc1 = sv1.x + sv1.y;

            // sigmoid(x) = rcp(1 + 2^(-x log2e)); tanh(x) = 2 sig(2x) - 1
            const float A = frcp(1.0f + fexp2(acc0));                   // i / f
            const float B = fmaf(bScl, frcp(1.0f + fexp2(acc1)), bOff); // g / o

            const float Asw = swap_half(A);      // f (lanes 0..31)
            const float Bsw = swap_half(B);      // o (lanes 0..31)

            c = fmaf(Asw, c, A * B);                              // c = f*c + i*g
            const float th = fmaf(2.0f,
                                  frcp(1.0f + fexp2(-2.0f * LOG2E * c)), -1.0f);
            h = Bsw * th;                                         // h = o*tanh(c)

            if (l < 32) hout[(size_t)idx * H + l] = h;

            idx += dir; ptr += step;
        }
    }
}

// ---------------------------------------------------------------------------
// Kernel C: output projection  out = [hf|hb] @ out_w.T + out_b
// ---------------------------------------------------------------------------
__global__ __launch_bounds__(64)
void out_kernel(const float* __restrict__ hf,
                const float* __restrict__ hb,
                const float* __restrict__ out_w,
                const float* __restrict__ out_b,
                float* __restrict__ out)
{
    __shared__ __align__(16) float hh[2 * H];
    const int s = blockIdx.x, tid = threadIdx.x;
    if (tid < H) hh[tid] = hf[(size_t)s * H + tid];
    else         hh[tid] = hb[(size_t)s * H + (tid - H)];
    __syncthreads();
    if (tid < NTAGS) {
        v4f av = {0.f, 0.f, 0.f, 0.f};
        const float* wrow = out_w + (size_t)tid * 2 * H;
#pragma unroll
        for (int jj = 0; jj < (2 * H) / 4; ++jj) {
            v4f wv = *(const v4f*)(wrow + 4 * jj);
            v4f hv = *(const v4f*)(&hh[4 * jj]);
            av = __builtin_elementwise_fma(wv, hv, av);
        }
        out[(size_t)s * NTAGS + tid] =
            out_b[tid] + (av.x + av.y) + (av.z + av.w);
    }
}

extern "C" void kernel_launch(void* const* d_in, const int* in_sizes, int n_in,
                              void* d_out, int out_size, void* d_ws, size_t ws_size,
                              hipStream_t stream) {
    const int*   word_ids = (const int*)  d_in[0];
    const int*   char_ids = (const int*)  d_in[1];
    const float* word_emb = (const float*)d_in[2];
    const float* char_emb = (const float*)d_in[3];
    const float* conv_w   = (const float*)d_in[4];
    const float* conv_b   = (const float*)d_in[5];
    const float* w_ih_f   = (const float*)d_in[6];
    const float* w_hh_f   = (const float*)d_in[7];
    const float* b_ih_f   = (const float*)d_in[8];
    const float* b_hh_f   = (const float*)d_in[9];
    const float* w_ih_b   = (const float*)d_in[10];
    const float* w_hh_b   = (const float*)d_in[11];
    const float* b_ih_b   = (const float*)d_in[12];
    const float* b_hh_b   = (const float*)d_in[13];
    const float* out_w    = (const float*)d_in[14];
    const float* out_b    = (const float*)d_in[15];
    float* out = (float*)d_out;

    float* ws    = (float*)d_ws;
    float* pre_f = ws;                         // S*128
    float* pre_b = pre_f + (size_t)S * 128;    // S*128
    float* hf    = pre_b + (size_t)S * 128;    // S*H
    float* hb    = hf    + (size_t)S * H;      // S*H
    float* wpad  = hb    + (size_t)S * H;      // 256*WPAD

    pad_w_kernel<<<256, 64, 0, stream>>>(w_ih_f, w_ih_b, wpad);
    prep_kernel<<<S, 256, 0, stream>>>(word_ids, char_ids, word_emb, char_emb,
                                       conv_w, conv_b, wpad,
                                       b_ih_f, b_hh_f, b_ih_b, b_hh_b,
                                       pre_f, pre_b);
    lstm_scan<<<2, 64, 0, stream>>>(pre_f, pre_b, w_hh_f, w_hh_b, hf, hb);
    out_kernel<<<S, 64, 0, stream>>>(hf, hb, out_w, out_b, out);
}

// Round 4
// 1199.682 us; speedup vs baseline: 1.7555x; 1.0381x over previous
//
#include <hip/hip_runtime.h>
#include <hip/hip_bf16.h>

#define S 4096
#define L 16
#define WD 128
#define CD 32
#define NF 5
#define KW 5
#define H 32
#define IN_DIM (WD + 5)    // 133
#define WPAD 136           // padded row stride (16B-aligned rows)
#define NTAGS 45

typedef float v2f __attribute__((ext_vector_type(2)));
typedef float v4f __attribute__((ext_vector_type(4)));

#define LOG2E 1.4426950408889634f

__device__ inline float fexp2(float x) { return __builtin_amdgcn_exp2f(x); }
__device__ inline float frcp(float x)  { return __builtin_amdgcn_rcpf(x); }
__device__ inline float rl(float v, int lane) {
    return __int_as_float(__builtin_amdgcn_readlane(__float_as_int(v), lane));
}

// exchange half-waves: returned value, in lanes 0..31, holds x's lanes 32..63.
__device__ inline float swap_half(float x) {
#if __has_builtin(__builtin_amdgcn_permlane32_swap)
    typedef unsigned uv2 __attribute__((ext_vector_type(2)));
    uv2 r = __builtin_amdgcn_permlane32_swap(__float_as_uint(x),
                                             __float_as_uint(x), false, false);
    return __uint_as_float(r.y);
#else
    return __shfl_xor(x, 32, 64);
#endif
}

// Force a v2f to live in an (even-aligned) VGPR pair as an opaque value the
// compiler cannot rematerialize (defeats in-loop reload of loop-invariants).
__device__ inline v2f pin_pair(v2f x) {
    double t = __builtin_bit_cast(double, x);
    asm volatile("" : "+v"(t));
    return __builtin_bit_cast(v2f, t);
}

// ---------------------------------------------------------------------------
// Kernel 0: pad w_ih rows (133 -> 136) so prep can use float4 loads
// ---------------------------------------------------------------------------
__global__ __launch_bounds__(64)
void pad_w_kernel(const float* __restrict__ wf, const float* __restrict__ wb,
                  float* __restrict__ wpad)
{
    const int r = blockIdx.x;
    const float* src = (r < 128) ? (wf + (size_t)r * IN_DIM)
                                 : (wb + (size_t)(r - 128) * IN_DIM);
    for (int j = threadIdx.x; j < WPAD; j += 64)
        wpad[(size_t)r * WPAD + j] = (j < IN_DIM) ? src[j] : 0.0f;
}

// ---------------------------------------------------------------------------
// Kernel A: feature build + input projection (both directions), pre-scaled by
// -log2e (and -2log2e for the tanh/g rows) so the scan's activations are
// exp2-ready with no on-chain multiply.
// ---------------------------------------------------------------------------
__global__ __launch_bounds__(256)
void prep_kernel(const int* __restrict__ word_ids,
                 const int* __restrict__ char_ids,
                 const float* __restrict__ word_emb,
                 const float* __restrict__ char_emb,
                 const float* __restrict__ conv_w,
                 const float* __restrict__ conv_b,
                 const float* __restrict__ wpad,     // [256][WPAD]
                 const float* __restrict__ b_ih_f,
                 const float* __restrict__ b_hh_f,
                 const float* __restrict__ b_ih_b,
                 const float* __restrict__ b_hh_b,
                 float* __restrict__ pre_f,
                 float* __restrict__ pre_b)
{
    __shared__ __align__(16) float rep[WPAD];
    __shared__ __align__(16) float ce[L][CD];
    __shared__ __align__(16) float cw[NF][KW][CD];
    __shared__ float convout[NF][L];

    const int s   = blockIdx.x;
    const int tid = threadIdx.x;
    const int wid = word_ids[s];

    if (tid < WD / 4)
        *(v4f*)&rep[4 * tid] = *(const v4f*)&word_emb[(size_t)wid * WD + 4 * tid];
    if (tid >= WD && tid < WPAD) rep[tid] = 0.0f;

    if (tid < L * CD / 4) {
        int l = tid / (CD / 4), c4 = tid % (CD / 4);
        *(v4f*)&ce[l][4 * c4] =
            *(const v4f*)&char_emb[(size_t)char_ids[s * L + l] * CD + 4 * c4];
    }
    for (int i = tid; i < NF * KW * CD; i += 256) {
        int f = i / (KW * CD), r = i % (KW * CD), k = r / CD, c = r % CD;
        cw[f][k][c] = conv_w[f * CD * KW + c * KW + k];
    }
    __syncthreads();

    if (tid < NF * L) {
        int f = tid / L, l = tid % L;
        v4f av = {0.f, 0.f, 0.f, 0.f};
#pragma unroll
        for (int k = 0; k < KW; ++k) {
            int ll = l + k - 2;
            if (ll >= 0 && ll < L) {
#pragma unroll
                for (int q = 0; q < CD / 4; ++q)
                    av = __builtin_elementwise_fma(*(const v4f*)&ce[ll][4 * q],
                                                   *(const v4f*)&cw[f][k][4 * q], av);
            }
        }
        convout[f][l] = conv_b[f] + (av.x + av.y) + (av.z + av.w);
    }
    __syncthreads();

    if (tid < NF) {
        float m = convout[tid][0];
#pragma unroll
        for (int l = 1; l < L; ++l) m = fmaxf(m, convout[tid][l]);
        rep[WD + tid] = m;
    }
    __syncthreads();

    {
        const int g = tid & 127;
        const bool fw = (tid < 128);
        const float* wrow = wpad + ((size_t)(fw ? g : g + 128)) * WPAD;
        float acc = fw ? (b_ih_f[g] + b_hh_f[g]) : (b_ih_b[g] + b_hh_b[g]);
        v4f av = {0.f, 0.f, 0.f, 0.f};
#pragma unroll
        for (int jj = 0; jj < WPAD / 4; ++jj) {
            v4f wv = *(const v4f*)(wrow + 4 * jj);
            v4f rv = *(const v4f*)(&rep[4 * jj]);
            av = __builtin_elementwise_fma(wv, rv, av);
        }
        acc += (av.x + av.y) + (av.z + av.w);
        const float scl = (g >= 64 && g < 96) ? (-2.0f * LOG2E) : (-LOG2E);
        (fw ? pre_f : pre_b)[(size_t)s * 128 + g] = acc * scl;
    }
}

// ---------------------------------------------------------------------------
// Kernel B: sequential LSTM scan. 2 blocks (fwd/bwd) x 64 threads.
// Weights pinned in VGPRs via opaque asm (anti-remat), permlane32_swap for the
// half exchange, packed FMA chains, prefetch depth 4, exp2-domain activations.
// ---------------------------------------------------------------------------
#define PF 4
__global__ __launch_bounds__(64, 1)
void lstm_scan(const float* __restrict__ pre_f,
               const float* __restrict__ pre_b,
               const float* __restrict__ w_hh_f,
               const float* __restrict__ w_hh_b,
               float* __restrict__ hf,
               float* __restrict__ hb)
{
    const bool fwd = (blockIdx.x == 0);
    const float* __restrict__ pre = fwd ? pre_f : pre_b;
    const float* __restrict__ whh = fwd ? w_hh_f : w_hh_b;
    float* __restrict__ hout      = fwd ? hf : hb;
    const int dir  = fwd ? 1 : -1;
    const int idx0 = fwd ? 0 : (S - 1);
    const int step = dir * 128;

    const int l  = threadIdx.x;      // 0..63
    const int g0 = l;                // i (l<32) / f (l>=32) : sigmoid
    const int g1 = l + 64;           // g (l<32) / o (l>=32) : tanh / sigmoid

    const bool isG = (l < 32);
    const float s0 = -LOG2E;
    const float s1 = isG ? (-2.0f * LOG2E) : (-LOG2E);
    const float bScl = isG ? 2.0f : 1.0f;
    const float bOff = isG ? -1.0f : 0.0f;

    // w_hh rows, scaled into exp2 domain, pinned resident in VGPR pairs
    v2f w0[H / 2], w1[H / 2];
    {
        const v2f* wr0 = (const v2f*)(whh + (size_t)g0 * H);
        const v2f* wr1 = (const v2f*)(whh + (size_t)g1 * H);
        v2f vs0; vs0.x = s0; vs0.y = s0;
        v2f vs1; vs1.x = s1; vs1.y = s1;
#pragma unroll
        for (int j = 0; j < H / 2; ++j) {
            w0[j] = pin_pair(wr0[j] * vs0);
            w1[j] = pin_pair(wr1[j] * vs1);
        }
    }

    float h = 0.0f, c = 0.0f;
    int idx = idx0;
    const float* ptr = pre + (size_t)idx0 * 128;

    float pp0[PF], pp1[PF];
#pragma unroll
    for (int u = 0; u < PF; ++u) {
        pp0[u] = ptr[(long)step * u + g0];
        pp1[u] = ptr[(long)step * u + g1];
    }

    for (int t = 0; t < S; t += PF) {
#pragma unroll
        for (int u = 0; u < PF; ++u) {
            const float cp0 = pp0[u], cp1 = pp1[u];
            pp0[u] = ptr[(long)step * PF + g0];   // refill PF steps ahead
            pp1[u] = ptr[(long)step * PF + g1];

            // acc = scaled_pre + h . scaled_w  — 4 independent chains of 8
            v2f a0a; a0a.x = cp0; a0a.y = 0.0f;
            v2f a1a; a1a.x = cp1; a1a.y = 0.0f;
            v2f a0b = {0.f, 0.f}, a1b = {0.f, 0.f};
#pragma unroll
            for (int jp = 0; jp < 8; ++jp) {
                v2f hpa, hpb;
                hpa.x = rl(h, 2 * jp);      hpa.y = rl(h, 2 * jp + 1);
                hpb.x = rl(h, 2 * jp + 16); hpb.y = rl(h, 2 * jp + 17);
                a0a = __builtin_elementwise_fma(hpa, w0[jp], a0a);
                a0b = __builtin_elementwise_fma(hpb, w0[jp + 8], a0b);
                a1a = __builtin_elementwise_fma(hpa, w1[jp], a1a);
                a1b = __builtin_elementwise_fma(hpb, w1[jp + 8], a1b);
            }
            const v2f sv0 = a0a + a0b;
            const v2f sv1 = a1a + a1b;
            const float acc0 = sv0.x + sv0.y;    // = -log2e * preact
            const float acc1 = sv1.x + sv1.y;

            const float A = frcp(1.0f + fexp2(acc0));                   // i / f
            const float B = fmaf(bScl, frcp(1.0f + fexp2(acc1)), bOff); // g / o

            const float Asw = swap_half(A);      // f (lanes 0..31)
            const float Bsw = swap_half(B);      // o (lanes 0..31)

            c = fmaf(Asw, c, A * B);                       // c = f*c + i*g
            // h = o*tanh(c) = fma(2o, sig(2c), -o); the Bsw products run
            // parallel to the c->exp2->rcp chain
            const float o2 = 2.0f * Bsw, on = -Bsw;
            const float r  = frcp(1.0f + fexp2(-2.0f * LOG2E * c));
            h = fmaf(o2, r, on);

            if (l < 32) hout[(size_t)idx * H + l] = h;

            idx += dir; ptr += step;
        }
    }
}

// ---------------------------------------------------------------------------
// Kernel C: output projection  out = [hf|hb] @ out_w.T + out_b
// ---------------------------------------------------------------------------
__global__ __launch_bounds__(64)
void out_kernel(const float* __restrict__ hf,
                const float* __restrict__ hb,
                const float* __restrict__ out_w,
                const float* __restrict__ out_b,
                float* __restrict__ out)
{
    __shared__ __align__(16) float hh[2 * H];
    const int s = blockIdx.x, tid = threadIdx.x;
    if (tid < H) hh[tid] = hf[(size_t)s * H + tid];
    else         hh[tid] = hb[(size_t)s * H + (tid - H)];
    __syncthreads();
    if (tid < NTAGS) {
        v4f av = {0.f, 0.f, 0.f, 0.f};
        const float* wrow = out_w + (size_t)tid * 2 * H;
#pragma unroll
        for (int jj = 0; jj < (2 * H) / 4; ++jj) {
            v4f wv = *(const v4f*)(wrow + 4 * jj);
            v4f hv = *(const v4f*)(&hh[4 * jj]);
            av = __builtin_elementwise_fma(wv, hv, av);
        }
        out[(size_t)s * NTAGS + tid] =
            out_b[tid] + (av.x + av.y) + (av.z + av.w);
    }
}

extern "C" void kernel_launch(void* const* d_in, const int* in_sizes, int n_in,
                              void* d_out, int out_size, void* d_ws, size_t ws_size,
                              hipStream_t stream) {
    const int*   word_ids = (const int*)  d_in[0];
    const int*   char_ids = (const int*)  d_in[1];
    const float* word_emb = (const float*)d_in[2];
    const float* char_emb = (const float*)d_in[3];
    const float* conv_w   = (const float*)d_in[4];
    const float* conv_b   = (const float*)d_in[5];
    const float* w_ih_f   = (const float*)d_in[6];
    const float* w_hh_f   = (const float*)d_in[7];
    const float* b_ih_f   = (const float*)d_in[8];
    const float* b_hh_f   = (const float*)d_in[9];
    const float* w_ih_b   = (const float*)d_in[10];
    const float* w_hh_b   = (const float*)d_in[11];
    const float* b_ih_b   = (const float*)d_in[12];
    const float* b_hh_b   = (const float*)d_in[13];
    const float* out_w    = (const float*)d_in[14];
    const float* out_b    = (const float*)d_in[15];
    float* out = (float*)d_out;

    float* ws    = (float*)d_ws;
    float* pre_f = ws;                         // S*128
    float* pre_b = pre_f + (size_t)S * 128;    // S*128
    float* hf    = pre_b + (size_t)S * 128;    // S*H
    float* hb    = hf    + (size_t)S * H;      // S*H
    float* wpad  = hb    + (size_t)S * H;      // 256*WPAD

    pad_w_kernel<<<256, 64, 0, stream>>>(w_ih_f, w_ih_b, wpad);
    prep_kernel<<<S, 256, 0, stream>>>(word_ids, char_ids, word_emb, char_emb,
                                       conv_w, conv_b, wpad,
                                       b_ih_f, b_hh_f, b_ih_b, b_hh_b,
                                       pre_f, pre_b);
    lstm_scan<<<2, 64, 0, stream>>>(pre_f, pre_b, w_hh_f, w_hh_b, hf, hb);
    out_kernel<<<S, 64, 0, stream>>>(hf, hb, out_w, out_b, out);
}